// Round 5
// baseline (540.689 us; speedup 1.0000x reference)
//
#include <hip/hip_runtime.h>
#include <math.h>

#define N_NODES 50000
#define N_EDGES 800000
#define EP (N_EDGES + N_NODES)   /* 850000 with self loops */
#define IN_CH 128
#define HID 64
#define HEADS 4
#define F1 (HEADS * HID)         /* 256 */
#define LAT 32
#define NEG 0.2f
#define NB_SCAN ((N_NODES + 255) / 256)   /* 196 blocks */
#define KB 32                     /* gemm1 k-chunk */

__device__ __forceinline__ unsigned short f2bf(float f) {
    unsigned int x = __float_as_uint(f);
    x += 0x7fffu + ((x >> 16) & 1u);       // round-to-nearest-even
    return (unsigned short)(x >> 16);
}
__device__ __forceinline__ float bf2f(unsigned short u) {
    return __uint_as_float(((unsigned int)u) << 16);
}

// ------- GEMM1: x(N,128) @ Wl/Wr(128,256) -> xlh (bf16 gather payload), xr (fp32) -------
__global__ __launch_bounds__(256, 4) void gemm1(const float* __restrict__ x,
                                                const float* __restrict__ Wl,
                                                const float* __restrict__ Wr,
                                                unsigned short* __restrict__ xlh,
                                                float* __restrict__ xr) {
    __shared__ float xsT[KB][68];
    __shared__ float wls[KB][64];
    __shared__ float wrs[KB][64];
    int t = threadIdx.x;
    int row0 = blockIdx.x * 64;
    int col0 = blockIdx.y * 64;
    int ty = t >> 4, tx = t & 15;
    int r0 = ty * 4, c0 = tx * 4;
    float accl[4][4] = {};
    float accr[4][4] = {};
    for (int k0 = 0; k0 < IN_CH; k0 += KB) {
#pragma unroll
        for (int i = 0; i < 2; i++) {
            int f = t + i * 256;
            int r = f >> 3;
            int kk = (f & 7) << 2;
            float4 v = make_float4(0.f, 0.f, 0.f, 0.f);
            if (row0 + r < N_NODES)
                v = *(const float4*)(x + (size_t)(row0 + r) * IN_CH + k0 + kk);
            xsT[kk + 0][r] = v.x;
            xsT[kk + 1][r] = v.y;
            xsT[kk + 2][r] = v.z;
            xsT[kk + 3][r] = v.w;
        }
#pragma unroll
        for (int i = 0; i < 2; i++) {
            int f = t + i * 256;
            int k = f >> 4;
            int c4 = (f & 15) << 2;
            *(float4*)&wls[k][c4] = *(const float4*)(Wl + (size_t)(k0 + k) * F1 + col0 + c4);
            *(float4*)&wrs[k][c4] = *(const float4*)(Wr + (size_t)(k0 + k) * F1 + col0 + c4);
        }
        __syncthreads();
#pragma unroll 8
        for (int k = 0; k < KB; k++) {
            float4 a4 = *(float4*)&xsT[k][r0];
            float4 bl = *(float4*)&wls[k][c0];
            float4 br = *(float4*)&wrs[k][c0];
            float a[4] = {a4.x, a4.y, a4.z, a4.w};
#pragma unroll
            for (int i = 0; i < 4; i++) {
                accl[i][0] += a[i] * bl.x; accl[i][1] += a[i] * bl.y;
                accl[i][2] += a[i] * bl.z; accl[i][3] += a[i] * bl.w;
                accr[i][0] += a[i] * br.x; accr[i][1] += a[i] * br.y;
                accr[i][2] += a[i] * br.z; accr[i][3] += a[i] * br.w;
            }
        }
        __syncthreads();
    }
#pragma unroll
    for (int i = 0; i < 4; i++) {
        int r = row0 + r0 + i;
        if (r < N_NODES) {
            *(float4*)(xr + (size_t)r * F1 + col0 + c0) =
                make_float4(accr[i][0], accr[i][1], accr[i][2], accr[i][3]);
            ushort4 u;
            u.x = f2bf(accl[i][0]); u.y = f2bf(accl[i][1]);
            u.z = f2bf(accl[i][2]); u.w = f2bf(accl[i][3]);
            *(ushort4*)(xlh + (size_t)r * F1 + col0 + c0) = u;
        }
    }
}

// ---------------- CSR build ----------------
__global__ void hist(const int* __restrict__ ei, int* __restrict__ deg) {
    long e = (long)blockIdx.x * 256 + threadIdx.x;
    if (e >= EP) return;
    int d = (e < N_EDGES) ? ei[N_EDGES + e] : (int)(e - N_EDGES);
    atomicAdd(&deg[d], 1);
}

__global__ void scan1(const int* __restrict__ deg, int* __restrict__ partial,
                      int* __restrict__ bsums) {
    __shared__ int tmp[256];
    int t = threadIdx.x;
    int i = blockIdx.x * 256 + t;
    tmp[t] = (i < N_NODES) ? deg[i] : 0;
    __syncthreads();
#pragma unroll
    for (int off = 1; off < 256; off <<= 1) {
        int v = (t >= off) ? tmp[t - off] : 0;
        __syncthreads();
        tmp[t] += v;
        __syncthreads();
    }
    if (i < N_NODES) partial[i] = tmp[t];
    if (t == 255) bsums[blockIdx.x] = tmp[255];
}

__global__ void scan2(int* __restrict__ bsums) {
    __shared__ int tmp[256];
    int t = threadIdx.x;
    tmp[t] = (t < NB_SCAN) ? bsums[t] : 0;
    __syncthreads();
#pragma unroll
    for (int off = 1; off < 256; off <<= 1) {
        int v = (t >= off) ? tmp[t - off] : 0;
        __syncthreads();
        tmp[t] += v;
        __syncthreads();
    }
    if (t < NB_SCAN) bsums[t] = tmp[t];
}

__global__ void scan3(const int* __restrict__ partial, const int* __restrict__ bsums,
                      const int* __restrict__ deg, int* __restrict__ row_start,
                      int* __restrict__ cur) {
    int i = blockIdx.x * 256 + threadIdx.x;
    if (i >= N_NODES) return;
    int add = (blockIdx.x > 0) ? bsums[blockIdx.x - 1] : 0;
    int excl = partial[i] + add - deg[i];
    row_start[i] = excl;
    cur[i] = excl;
}

__global__ void scatter_csr(const int* __restrict__ ei, int* __restrict__ cur,
                            int* __restrict__ srcs) {
    long e = (long)blockIdx.x * 256 + threadIdx.x;
    if (e >= EP) return;
    int s, d;
    if (e < N_EDGES) { s = ei[e]; d = ei[N_EDGES + e]; }
    else             { s = d = (int)(e - N_EDGES); }
    int pos = atomicAdd(&cur[d], 1);
    srcs[pos] = s;
}

// ------- fused L1: per-dst softmax aggregation + bias + ELU (in place) -------
// Fixed-reference softmax (scores bounded ~|7| -> exp never overflows; softmax is
// shift-invariant so result matches the max-subtracted reference to fp32 rounding).
// Scalarized loop control: d is wave-uniform -> start/dg in SGPRs, srcs via s_load.
__global__ __launch_bounds__(256) void fused_l1(const unsigned short* __restrict__ xlh,
                                                float* __restrict__ xr_h,
                                                const int* __restrict__ srcs,
                                                const int* __restrict__ row_start,
                                                const int* __restrict__ deg,
                                                const float* __restrict__ att,
                                                const float* __restrict__ bias) {
    int wave = threadIdx.x >> 6;
    int lane = threadIdx.x & 63;
    int d = blockIdx.x * 4 + wave;
    if (d >= N_NODES) return;
    int c0 = lane << 2;                 // 4 channels per lane; head = lane>>4
    float4 xr4 = *(const float4*)(xr_h + (size_t)d * F1 + c0);
    float4 at4 = *(const float4*)(att + c0);
    int start = __builtin_amdgcn_readfirstlane(row_start[d]);
    int dg    = __builtin_amdgcn_readfirstlane(deg[d]);
    int last  = dg - 1;
    float l = 0.f;
    float4 acc = make_float4(0.f, 0.f, 0.f, 0.f);
    // depth-2 pipeline, tail prefetches clamped to the last valid edge
    int sB = srcs[start];
    ushort4 raw = *(const ushort4*)(xlh + (size_t)sB * F1 + c0);
    sB = srcs[start + min(1, last)];
    for (int j = 0; j < dg; j++) {
        ushort4 cr = raw;
        raw = *(const ushort4*)(xlh + (size_t)sB * F1 + c0);
        sB = srcs[start + min(j + 2, last)];
        float ax = bf2f(cr.x), ay = bf2f(cr.y), az = bf2f(cr.z), aw = bf2f(cr.w);
        float v0 = ax + xr4.x; v0 = fmaxf(v0, NEG * v0);
        float v1 = ay + xr4.y; v1 = fmaxf(v1, NEG * v1);
        float v2 = az + xr4.z; v2 = fmaxf(v2, NEG * v2);
        float v3 = aw + xr4.w; v3 = fmaxf(v3, NEG * v3);
        float sc = v0 * at4.x + v1 * at4.y + v2 * at4.z + v3 * at4.w;
        sc += __shfl_xor(sc, 1);
        sc += __shfl_xor(sc, 2);
        sc += __shfl_xor(sc, 4);
        sc += __shfl_xor(sc, 8);
        float ex = __expf(sc);
        l += ex;
        acc.x += ex * ax;
        acc.y += ex * ay;
        acc.z += ex * az;
        acc.w += ex * aw;
    }
    float inv = 1.0f / l;
    float4 b4 = *(const float4*)(bias + c0);
    float o0 = acc.x * inv + b4.x; o0 = o0 > 0.f ? o0 : __expf(o0) - 1.0f;
    float o1 = acc.y * inv + b4.y; o1 = o1 > 0.f ? o1 : __expf(o1) - 1.0f;
    float o2 = acc.z * inv + b4.z; o2 = o2 > 0.f ? o2 : __expf(o2) - 1.0f;
    float o3 = acc.w * inv + b4.w; o3 = o3 > 0.f ? o3 : __expf(o3) - 1.0f;
    *(float4*)(xr_h + (size_t)d * F1 + c0) = make_float4(o0, o1, o2, o3);
}

// ---------------- GEMM2: h(N,256) @ Wl2/Wr2(256,32) -> xl2, xr2 ----------------
__global__ __launch_bounds__(256) void gemm2(const float* __restrict__ h,
                                             const float* __restrict__ Wl,
                                             const float* __restrict__ Wr,
                                             float* __restrict__ xl2,
                                             float* __restrict__ xr2) {
    __shared__ float hs[16][256];
    int t = threadIdx.x;
    int row0 = blockIdx.x * 16;
#pragma unroll
    for (int i = 0; i < 4; i++) {
        int f = t + i * 256;
        int r = f >> 6;
        int k4 = (f & 63) << 2;
        float4 v = make_float4(0.f, 0.f, 0.f, 0.f);
        if (row0 + r < N_NODES)
            v = *(const float4*)(h + (size_t)(row0 + r) * F1 + k4);
        *(float4*)&hs[r][k4] = v;
    }
    __syncthreads();
    int c = t & 31, rl = t >> 5;
    float al0 = 0.f, ar0 = 0.f, al1 = 0.f, ar1 = 0.f;
    for (int k = 0; k < F1; k++) {
        float wl = Wl[k * LAT + c];
        float wr = Wr[k * LAT + c];
        float h0 = hs[rl][k];
        float h1 = hs[rl + 8][k];
        al0 += h0 * wl; ar0 += h0 * wr;
        al1 += h1 * wl; ar1 += h1 * wr;
    }
    int r = row0 + rl;
    if (r < N_NODES) {
        xl2[(size_t)r * LAT + c] = al0;
        xr2[(size_t)r * LAT + c] = ar0;
    }
    if (r + 8 < N_NODES) {
        xl2[(size_t)(r + 8) * LAT + c] = al1;
        xr2[(size_t)(r + 8) * LAT + c] = ar1;
    }
}

// ------- fused L2: per-dst softmax aggregation + bias (heads=1, 32 ch) -------
__global__ __launch_bounds__(256) void fused_l2(const float* __restrict__ xl2,
                                                const float* __restrict__ xr2,
                                                const int* __restrict__ srcs,
                                                const int* __restrict__ row_start,
                                                const int* __restrict__ deg,
                                                const float* __restrict__ att,
                                                const float* __restrict__ bias,
                                                float* __restrict__ z) {
    int sub = threadIdx.x >> 5;
    int lane = threadIdx.x & 31;
    int d = blockIdx.x * 8 + sub;
    if (d >= N_NODES) return;
    float xr = xr2[(size_t)d * LAT + lane];
    float av = att[lane];
    int start = row_start[d];
    int dg = deg[d];
    int last = dg - 1;
    float l = 0.f, acc = 0.f;
    int sB = srcs[start];
    float a_next = xl2[(size_t)sB * LAT + lane];
    sB = srcs[start + min(1, last)];
    for (int j = 0; j < dg; j++) {
        float a = a_next;
        a_next = xl2[(size_t)sB * LAT + lane];
        sB = srcs[start + min(j + 2, last)];
        float v = a + xr; v = fmaxf(v, NEG * v);
        float sc = v * av;
        sc += __shfl_xor(sc, 1);
        sc += __shfl_xor(sc, 2);
        sc += __shfl_xor(sc, 4);
        sc += __shfl_xor(sc, 8);
        sc += __shfl_xor(sc, 16);
        float ex = __expf(sc);
        l += ex;
        acc += ex * a;
    }
    z[(size_t)d * LAT + lane] = acc / l + bias[lane];
}

// ---------------- decode: sigmoid(<z[row], z[col]>) over original edges ----------------
__global__ __launch_bounds__(256) void decode(const float* __restrict__ z,
                                              const int* __restrict__ ei,
                                              float* __restrict__ out) {
    int lane = threadIdx.x & 31;
    long e = (long)blockIdx.x * 8 + (threadIdx.x >> 5);
    if (e >= N_EDGES) return;
    int r = ei[e], c = ei[N_EDGES + e];
    float v = z[(size_t)r * LAT + lane] * z[(size_t)c * LAT + lane];
#pragma unroll
    for (int off = 16; off > 0; off >>= 1) v += __shfl_xor(v, off);
    if (lane == 0) out[e] = 1.0f / (1.0f + __expf(-v));
}

extern "C" void kernel_launch(void* const* d_in, const int* in_sizes, int n_in,
                              void* d_out, int out_size, void* d_ws, size_t ws_size,
                              hipStream_t stream) {
    const float* x    = (const float*)d_in[0];
    const int*   ei   = (const int*)d_in[1];
    const float* Wl1  = (const float*)d_in[2];
    const float* Wr1  = (const float*)d_in[3];
    const float* att1 = (const float*)d_in[4];
    const float* b1   = (const float*)d_in[5];
    const float* Wl2  = (const float*)d_in[6];
    const float* Wr2  = (const float*)d_in[7];
    const float* att2 = (const float*)d_in[8];
    const float* b2   = (const float*)d_in[9];
    float* out = (float*)d_out;

    float* ws   = (float*)d_ws;
    float* xr1  = ws;                                  // N*256 fp32 -> becomes h in place
    unsigned short* xlh = (unsigned short*)(xr1 + (size_t)N_NODES * F1);  // N*256 bf16
    int* deg       = (int*)(xlh + (size_t)N_NODES * F1);
    int* row_start = deg + N_NODES;
    int* cur       = row_start + N_NODES;
    int* partial   = cur + N_NODES;
    int* bsums     = partial + N_NODES;
    int* srcs      = bsums + 256;                      // EP ints (3.4 MB)
    // layer-2 buffers reuse the xlh region (dead after fused_l1): need 19.2 MB <= 25.6 MB
    float* xl2 = (float*)xlh;                          // N*32
    float* xr2 = xl2 + (size_t)N_NODES * LAT;
    float* z   = xr2 + (size_t)N_NODES * LAT;

    // ---- CSR build (graph is identical for both layers) ----
    hipMemsetAsync(deg, 0, N_NODES * sizeof(int), stream);
    gemm1<<<dim3((N_NODES + 63) / 64, F1 / 64), 256, 0, stream>>>(x, Wl1, Wr1, xlh, xr1);
    hist<<<(EP + 255) / 256, 256, 0, stream>>>(ei, deg);
    scan1<<<NB_SCAN, 256, 0, stream>>>(deg, partial, bsums);
    scan2<<<1, 256, 0, stream>>>(bsums);
    scan3<<<NB_SCAN, 256, 0, stream>>>(partial, bsums, deg, row_start, cur);
    scatter_csr<<<(EP + 255) / 256, 256, 0, stream>>>(ei, cur, srcs);

    // ---- layer 1 (fused softmax-aggregate, writes h over xr1) ----
    fused_l1<<<(N_NODES + 3) / 4, 256, 0, stream>>>(xlh, xr1, srcs, row_start, deg, att1, b1);

    // ---- layer 2 ----
    gemm2<<<(N_NODES + 15) / 16, 256, 0, stream>>>(xr1, Wl2, Wr2, xl2, xr2);
    fused_l2<<<(N_NODES + 7) / 8, 256, 0, stream>>>(xl2, xr2, srcs, row_start, deg, att2, b2, z);

    // ---- decode ----
    decode<<<(N_EDGES + 7) / 8, 256, 0, stream>>>(z, ei, out);
}

// Round 6
// 461.328 us; speedup vs baseline: 1.1720x; 1.1720x over previous
//
#include <hip/hip_runtime.h>
#include <hip/hip_fp16.h>
#include <math.h>

#define N_NODES 50000
#define N_EDGES 800000
#define EP (N_EDGES + N_NODES)   /* 850000 with self loops */
#define IN_CH 128
#define HID 64
#define HEADS 4
#define F1 (HEADS * HID)         /* 256 */
#define LAT 32
#define NEG 0.2f
#define NB_SCAN ((N_NODES + 255) / 256)   /* 196 blocks */
#define KB 32                     /* gemm1 k-chunk */

__device__ __forceinline__ unsigned short f2bf(float f) {
    unsigned int x = __float_as_uint(f);
    x += 0x7fffu + ((x >> 16) & 1u);       // round-to-nearest-even
    return (unsigned short)(x >> 16);
}
__device__ __forceinline__ float bf2f(unsigned short u) {
    return __uint_as_float(((unsigned int)u) << 16);
}

// ------- GEMM1: x(N,128) @ Wl/Wr(128,256) -> xlh (bf16 gather payload), xr (fp32) -------
__global__ __launch_bounds__(256, 4) void gemm1(const float* __restrict__ x,
                                                const float* __restrict__ Wl,
                                                const float* __restrict__ Wr,
                                                unsigned short* __restrict__ xlh,
                                                float* __restrict__ xr) {
    __shared__ float xsT[KB][68];
    __shared__ float wls[KB][64];
    __shared__ float wrs[KB][64];
    int t = threadIdx.x;
    int row0 = blockIdx.x * 64;
    int col0 = blockIdx.y * 64;
    int ty = t >> 4, tx = t & 15;
    int r0 = ty * 4, c0 = tx * 4;
    float accl[4][4] = {};
    float accr[4][4] = {};
    for (int k0 = 0; k0 < IN_CH; k0 += KB) {
#pragma unroll
        for (int i = 0; i < 2; i++) {
            int f = t + i * 256;
            int r = f >> 3;
            int kk = (f & 7) << 2;
            float4 v = make_float4(0.f, 0.f, 0.f, 0.f);
            if (row0 + r < N_NODES)
                v = *(const float4*)(x + (size_t)(row0 + r) * IN_CH + k0 + kk);
            xsT[kk + 0][r] = v.x;
            xsT[kk + 1][r] = v.y;
            xsT[kk + 2][r] = v.z;
            xsT[kk + 3][r] = v.w;
        }
#pragma unroll
        for (int i = 0; i < 2; i++) {
            int f = t + i * 256;
            int k = f >> 4;
            int c4 = (f & 15) << 2;
            *(float4*)&wls[k][c4] = *(const float4*)(Wl + (size_t)(k0 + k) * F1 + col0 + c4);
            *(float4*)&wrs[k][c4] = *(const float4*)(Wr + (size_t)(k0 + k) * F1 + col0 + c4);
        }
        __syncthreads();
#pragma unroll 8
        for (int k = 0; k < KB; k++) {
            float4 a4 = *(float4*)&xsT[k][r0];
            float4 bl = *(float4*)&wls[k][c0];
            float4 br = *(float4*)&wrs[k][c0];
            float a[4] = {a4.x, a4.y, a4.z, a4.w};
#pragma unroll
            for (int i = 0; i < 4; i++) {
                accl[i][0] += a[i] * bl.x; accl[i][1] += a[i] * bl.y;
                accl[i][2] += a[i] * bl.z; accl[i][3] += a[i] * bl.w;
                accr[i][0] += a[i] * br.x; accr[i][1] += a[i] * br.y;
                accr[i][2] += a[i] * br.z; accr[i][3] += a[i] * br.w;
            }
        }
        __syncthreads();
    }
#pragma unroll
    for (int i = 0; i < 4; i++) {
        int r = row0 + r0 + i;
        if (r < N_NODES) {
            *(float4*)(xr + (size_t)r * F1 + col0 + c0) =
                make_float4(accr[i][0], accr[i][1], accr[i][2], accr[i][3]);
            ushort4 u;
            u.x = f2bf(accl[i][0]); u.y = f2bf(accl[i][1]);
            u.z = f2bf(accl[i][2]); u.w = f2bf(accl[i][3]);
            *(ushort4*)(xlh + (size_t)r * F1 + col0 + c0) = u;
        }
    }
}

// ---------------- CSR build ----------------
__global__ void hist(const int* __restrict__ ei, int* __restrict__ deg) {
    long e = (long)blockIdx.x * 256 + threadIdx.x;
    if (e >= EP) return;
    int d = (e < N_EDGES) ? ei[N_EDGES + e] : (int)(e - N_EDGES);
    atomicAdd(&deg[d], 1);
}

__global__ void scan1(const int* __restrict__ deg, int* __restrict__ partial,
                      int* __restrict__ bsums) {
    __shared__ int tmp[256];
    int t = threadIdx.x;
    int i = blockIdx.x * 256 + t;
    tmp[t] = (i < N_NODES) ? deg[i] : 0;
    __syncthreads();
#pragma unroll
    for (int off = 1; off < 256; off <<= 1) {
        int v = (t >= off) ? tmp[t - off] : 0;
        __syncthreads();
        tmp[t] += v;
        __syncthreads();
    }
    if (i < N_NODES) partial[i] = tmp[t];
    if (t == 255) bsums[blockIdx.x] = tmp[255];
}

__global__ void scan2(int* __restrict__ bsums) {
    __shared__ int tmp[256];
    int t = threadIdx.x;
    tmp[t] = (t < NB_SCAN) ? bsums[t] : 0;
    __syncthreads();
#pragma unroll
    for (int off = 1; off < 256; off <<= 1) {
        int v = (t >= off) ? tmp[t - off] : 0;
        __syncthreads();
        tmp[t] += v;
        __syncthreads();
    }
    if (t < NB_SCAN) bsums[t] = tmp[t];
}

__global__ void scan3(const int* __restrict__ partial, const int* __restrict__ bsums,
                      const int* __restrict__ deg, int* __restrict__ row_start,
                      int* __restrict__ cur) {
    int i = blockIdx.x * 256 + threadIdx.x;
    if (i >= N_NODES) return;
    int add = (blockIdx.x > 0) ? bsums[blockIdx.x - 1] : 0;
    int excl = partial[i] + add - deg[i];
    row_start[i] = excl;
    cur[i] = excl;
}

__global__ void scatter_csr(const int* __restrict__ ei, int* __restrict__ cur,
                            int* __restrict__ srcs) {
    long e = (long)blockIdx.x * 256 + threadIdx.x;
    if (e >= EP) return;
    int s, d;
    if (e < N_EDGES) { s = ei[e]; d = ei[N_EDGES + e]; }
    else             { s = d = (int)(e - N_EDGES); }
    int pos = atomicAdd(&cur[d], 1);
    srcs[pos] = s;
}

// ------- fused L1: per-dst softmax aggregation + bias + ELU (in place) -------
// Fixed-reference softmax (associative) -> pair-unrolled edges with independent
// accumulators: 2 gathers + 2 prefetches in flight per wave (MLP 4).
__global__ __launch_bounds__(256) void fused_l1(const unsigned short* __restrict__ xlh,
                                                float* __restrict__ xr_h,
                                                const int* __restrict__ srcs,
                                                const int* __restrict__ row_start,
                                                const int* __restrict__ deg,
                                                const float* __restrict__ att,
                                                const float* __restrict__ bias) {
    int wave = threadIdx.x >> 6;
    int lane = threadIdx.x & 63;
    int d = blockIdx.x * 4 + wave;
    if (d >= N_NODES) return;
    int c0 = lane << 2;                 // 4 channels per lane; head = lane>>4
    float4 xr4 = *(const float4*)(xr_h + (size_t)d * F1 + c0);
    float4 at4 = *(const float4*)(att + c0);
    int start = __builtin_amdgcn_readfirstlane(row_start[d]);
    int dg    = __builtin_amdgcn_readfirstlane(deg[d]);
    int last  = dg - 1;
    float l0 = 0.f, l1 = 0.f;
    float4 acc0 = make_float4(0.f, 0.f, 0.f, 0.f);
    float4 acc1 = make_float4(0.f, 0.f, 0.f, 0.f);
    // prologue: rows for edges 0,1 (clamped)
    int sA = srcs[start];
    int sB = srcs[start + min(1, last)];
    ushort4 rawA = *(const ushort4*)(xlh + (size_t)sA * F1 + c0);
    ushort4 rawB = *(const ushort4*)(xlh + (size_t)sB * F1 + c0);
    int npairs = dg >> 1;
    for (int k = 0; k < npairs; k++) {
        int j = 2 * k;
        ushort4 cA = rawA, cB = rawB;
        int nA = srcs[start + min(j + 2, last)];
        int nB = srcs[start + min(j + 3, last)];
        rawA = *(const ushort4*)(xlh + (size_t)nA * F1 + c0);
        rawB = *(const ushort4*)(xlh + (size_t)nB * F1 + c0);
        // edge j
        {
            float ax = bf2f(cA.x), ay = bf2f(cA.y), az = bf2f(cA.z), aw = bf2f(cA.w);
            float v0 = ax + xr4.x; v0 = fmaxf(v0, NEG * v0);
            float v1 = ay + xr4.y; v1 = fmaxf(v1, NEG * v1);
            float v2 = az + xr4.z; v2 = fmaxf(v2, NEG * v2);
            float v3 = aw + xr4.w; v3 = fmaxf(v3, NEG * v3);
            float sc = v0 * at4.x + v1 * at4.y + v2 * at4.z + v3 * at4.w;
            sc += __shfl_xor(sc, 1);
            sc += __shfl_xor(sc, 2);
            sc += __shfl_xor(sc, 4);
            sc += __shfl_xor(sc, 8);
            float ex = __expf(sc);
            l0 += ex;
            acc0.x += ex * ax; acc0.y += ex * ay;
            acc0.z += ex * az; acc0.w += ex * aw;
        }
        // edge j+1
        {
            float ax = bf2f(cB.x), ay = bf2f(cB.y), az = bf2f(cB.z), aw = bf2f(cB.w);
            float v0 = ax + xr4.x; v0 = fmaxf(v0, NEG * v0);
            float v1 = ay + xr4.y; v1 = fmaxf(v1, NEG * v1);
            float v2 = az + xr4.z; v2 = fmaxf(v2, NEG * v2);
            float v3 = aw + xr4.w; v3 = fmaxf(v3, NEG * v3);
            float sc = v0 * at4.x + v1 * at4.y + v2 * at4.z + v3 * at4.w;
            sc += __shfl_xor(sc, 1);
            sc += __shfl_xor(sc, 2);
            sc += __shfl_xor(sc, 4);
            sc += __shfl_xor(sc, 8);
            float ex = __expf(sc);
            l1 += ex;
            acc1.x += ex * ax; acc1.y += ex * ay;
            acc1.z += ex * az; acc1.w += ex * aw;
        }
    }
    if (dg & 1) {  // tail edge row is in rawA (prefetch clamped to last)
        float ax = bf2f(rawA.x), ay = bf2f(rawA.y), az = bf2f(rawA.z), aw = bf2f(rawA.w);
        float v0 = ax + xr4.x; v0 = fmaxf(v0, NEG * v0);
        float v1 = ay + xr4.y; v1 = fmaxf(v1, NEG * v1);
        float v2 = az + xr4.z; v2 = fmaxf(v2, NEG * v2);
        float v3 = aw + xr4.w; v3 = fmaxf(v3, NEG * v3);
        float sc = v0 * at4.x + v1 * at4.y + v2 * at4.z + v3 * at4.w;
        sc += __shfl_xor(sc, 1);
        sc += __shfl_xor(sc, 2);
        sc += __shfl_xor(sc, 4);
        sc += __shfl_xor(sc, 8);
        float ex = __expf(sc);
        l0 += ex;
        acc0.x += ex * ax; acc0.y += ex * ay;
        acc0.z += ex * az; acc0.w += ex * aw;
    }
    float inv = 1.0f / (l0 + l1);
    float4 b4 = *(const float4*)(bias + c0);
    float o0 = (acc0.x + acc1.x) * inv + b4.x; o0 = o0 > 0.f ? o0 : __expf(o0) - 1.0f;
    float o1 = (acc0.y + acc1.y) * inv + b4.y; o1 = o1 > 0.f ? o1 : __expf(o1) - 1.0f;
    float o2 = (acc0.z + acc1.z) * inv + b4.z; o2 = o2 > 0.f ? o2 : __expf(o2) - 1.0f;
    float o3 = (acc0.w + acc1.w) * inv + b4.w; o3 = o3 > 0.f ? o3 : __expf(o3) - 1.0f;
    *(float4*)(xr_h + (size_t)d * F1 + c0) = make_float4(o0, o1, o2, o3);
}

// ---- GEMM2: h(N,256) @ Wl2/Wr2(256,32) -> xl2h (fp16 gather payload), xr2 (fp32) ----
__global__ __launch_bounds__(256) void gemm2(const float* __restrict__ h,
                                             const float* __restrict__ Wl,
                                             const float* __restrict__ Wr,
                                             __half* __restrict__ xl2h,
                                             float* __restrict__ xr2) {
    __shared__ float hs[16][256];
    int t = threadIdx.x;
    int row0 = blockIdx.x * 16;
#pragma unroll
    for (int i = 0; i < 4; i++) {
        int f = t + i * 256;
        int r = f >> 6;
        int k4 = (f & 63) << 2;
        float4 v = make_float4(0.f, 0.f, 0.f, 0.f);
        if (row0 + r < N_NODES)
            v = *(const float4*)(h + (size_t)(row0 + r) * F1 + k4);
        *(float4*)&hs[r][k4] = v;
    }
    __syncthreads();
    int c = t & 31, rl = t >> 5;
    float al0 = 0.f, ar0 = 0.f, al1 = 0.f, ar1 = 0.f;
    for (int k = 0; k < F1; k++) {
        float wl = Wl[k * LAT + c];
        float wr = Wr[k * LAT + c];
        float h0 = hs[rl][k];
        float h1 = hs[rl + 8][k];
        al0 += h0 * wl; ar0 += h0 * wr;
        al1 += h1 * wl; ar1 += h1 * wr;
    }
    int r = row0 + rl;
    if (r < N_NODES) {
        xl2h[(size_t)r * LAT + c] = __float2half_rn(al0);
        xr2[(size_t)r * LAT + c] = ar0;
    }
    if (r + 8 < N_NODES) {
        xl2h[(size_t)(r + 8) * LAT + c] = __float2half_rn(al1);
        xr2[(size_t)(r + 8) * LAT + c] = ar1;
    }
}

// ------- fused L2: one dst per wave; lanes 0-31 = even edges, 32-63 = odd edges -------
__global__ __launch_bounds__(256) void fused_l2(const __half* __restrict__ xl2h,
                                                const float* __restrict__ xr2,
                                                const int* __restrict__ srcs,
                                                const int* __restrict__ row_start,
                                                const int* __restrict__ deg,
                                                const float* __restrict__ att,
                                                const float* __restrict__ bias,
                                                __half* __restrict__ zh) {
    int wave = threadIdx.x >> 6;
    int lane = threadIdx.x & 63;
    int half = lane >> 5;
    int c = lane & 31;
    int d = blockIdx.x * 4 + wave;
    if (d >= N_NODES) return;
    float xr = xr2[(size_t)d * LAT + c];
    float av = att[c];
    int start = __builtin_amdgcn_readfirstlane(row_start[d]);
    int dg    = __builtin_amdgcn_readfirstlane(deg[d]);
    int last  = dg - 1;
    float l = 0.f, acc = 0.f;
    int jj = half;
    int sA = srcs[start + min(jj, last)];
    float aA = __half2float(xl2h[(size_t)sA * LAT + c]);
    int sN = srcs[start + min(jj + 2, last)];
    int iters = (dg + 1) >> 1;
    for (int k = 0; k < iters; k++) {
        float a = aA;
        aA = __half2float(xl2h[(size_t)sN * LAT + c]);
        sN = srcs[start + min(jj + 4, last)];
        float v = a + xr; v = fmaxf(v, NEG * v);
        float sc = v * av;
        sc += __shfl_xor(sc, 1);
        sc += __shfl_xor(sc, 2);
        sc += __shfl_xor(sc, 4);
        sc += __shfl_xor(sc, 8);
        sc += __shfl_xor(sc, 16);
        float ex = (jj < dg) ? __expf(sc) : 0.f;
        l += ex;
        acc += ex * a;
        jj += 2;
    }
    // combine halves
    l += __shfl_xor(l, 32);
    acc += __shfl_xor(acc, 32);
    if (half == 0)
        zh[(size_t)d * LAT + c] = __float2half_rn(acc / l + bias[c]);
}

// ------- decode: sigmoid(<z[row], z[col]>), z fp16, 16 lanes / edge, half2 loads -------
__global__ __launch_bounds__(256) void decode(const __half* __restrict__ zh,
                                              const int* __restrict__ ei,
                                              float* __restrict__ out) {
    int g = threadIdx.x >> 4;             // 16 groups per block
    int lane = threadIdx.x & 15;
    long e = (long)blockIdx.x * 16 + g;
    if (e >= N_EDGES) return;
    int r = ei[e], c = ei[N_EDGES + e];
    int cc = lane << 1;
    __half2 zr = *(const __half2*)(zh + (size_t)r * LAT + cc);
    __half2 zc = *(const __half2*)(zh + (size_t)c * LAT + cc);
    float v = __half2float(zr.x) * __half2float(zc.x)
            + __half2float(zr.y) * __half2float(zc.y);
    v += __shfl_xor(v, 1);
    v += __shfl_xor(v, 2);
    v += __shfl_xor(v, 4);
    v += __shfl_xor(v, 8);
    if (lane == 0) out[e] = 1.0f / (1.0f + __expf(-v));
}

extern "C" void kernel_launch(void* const* d_in, const int* in_sizes, int n_in,
                              void* d_out, int out_size, void* d_ws, size_t ws_size,
                              hipStream_t stream) {
    const float* x    = (const float*)d_in[0];
    const int*   ei   = (const int*)d_in[1];
    const float* Wl1  = (const float*)d_in[2];
    const float* Wr1  = (const float*)d_in[3];
    const float* att1 = (const float*)d_in[4];
    const float* b1   = (const float*)d_in[5];
    const float* Wl2  = (const float*)d_in[6];
    const float* Wr2  = (const float*)d_in[7];
    const float* att2 = (const float*)d_in[8];
    const float* b2   = (const float*)d_in[9];
    float* out = (float*)d_out;

    float* ws   = (float*)d_ws;
    float* xr1  = ws;                                  // N*256 fp32 -> becomes h in place
    unsigned short* xlh = (unsigned short*)(xr1 + (size_t)N_NODES * F1);  // N*256 bf16
    int* deg       = (int*)(xlh + (size_t)N_NODES * F1);
    int* row_start = deg + N_NODES;
    int* cur       = row_start + N_NODES;
    int* partial   = cur + N_NODES;
    int* bsums     = partial + N_NODES;
    int* srcs      = bsums + 256;                      // EP ints (3.4 MB)
    // layer-2 buffers reuse the xlh region (dead after fused_l1): 12.8 MB <= 25.6 MB
    __half* xl2h = (__half*)xlh;                       // N*32 fp16
    float*  xr2  = (float*)(xl2h + (size_t)N_NODES * LAT);
    __half* zh   = (__half*)(xr2 + (size_t)N_NODES * LAT);

    // ---- CSR build (graph is identical for both layers) ----
    hipMemsetAsync(deg, 0, N_NODES * sizeof(int), stream);
    gemm1<<<dim3((N_NODES + 63) / 64, F1 / 64), 256, 0, stream>>>(x, Wl1, Wr1, xlh, xr1);
    hist<<<(EP + 255) / 256, 256, 0, stream>>>(ei, deg);
    scan1<<<NB_SCAN, 256, 0, stream>>>(deg, partial, bsums);
    scan2<<<1, 256, 0, stream>>>(bsums);
    scan3<<<NB_SCAN, 256, 0, stream>>>(partial, bsums, deg, row_start, cur);
    scatter_csr<<<(EP + 255) / 256, 256, 0, stream>>>(ei, cur, srcs);

    // ---- layer 1 (fused softmax-aggregate, writes h over xr1) ----
    fused_l1<<<(N_NODES + 3) / 4, 256, 0, stream>>>(xlh, xr1, srcs, row_start, deg, att1, b1);

    // ---- layer 2 ----
    gemm2<<<(N_NODES + 15) / 16, 256, 0, stream>>>(xr1, Wl2, Wr2, xl2h, xr2);
    fused_l2<<<(N_NODES + 3) / 4, 256, 0, stream>>>(xl2h, xr2, srcs, row_start, deg, att2, b2, zh);

    // ---- decode ----
    decode<<<(N_EDGES + 15) / 16, 256, 0, stream>>>(zh, ei, out);
}

// Round 7
// 397.890 us; speedup vs baseline: 1.3589x; 1.1594x over previous
//
#include <hip/hip_runtime.h>
#include <hip/hip_fp16.h>
#include <math.h>

#define N_NODES 50000
#define N_EDGES 800000
#define EP (N_EDGES + N_NODES)   /* 850000 with self loops */
#define IN_CH 128
#define HID 64
#define HEADS 4
#define F1 (HEADS * HID)         /* 256 */
#define LAT 32
#define NEG 0.2f
#define NB_SCAN ((N_NODES + 255) / 256)   /* 196 blocks */

typedef __attribute__((ext_vector_type(8))) short short8;
typedef __attribute__((ext_vector_type(4))) float f32x4;

__device__ __forceinline__ unsigned short f2bf(float f) {
    unsigned int x = __float_as_uint(f);
    x += 0x7fffu + ((x >> 16) & 1u);       // round-to-nearest-even
    return (unsigned short)(x >> 16);
}
__device__ __forceinline__ float bf2f(unsigned short u) {
    return __uint_as_float(((unsigned int)u) << 16);
}
__device__ __forceinline__ f32x4 mfma_bf16(short8 a, short8 b, f32x4 c) {
    return __builtin_amdgcn_mfma_f32_16x16x32_bf16(a, b, c, 0, 0, 0);
}

// ---------------- prep: fp32 -> bf16 conversions ----------------
__global__ void conv_x(const float* __restrict__ x, unsigned short* __restrict__ xbf) {
    int i = blockIdx.x * 256 + threadIdx.x;          // one float4 per thread
    if (i >= N_NODES * IN_CH / 4) return;
    float4 v = *(const float4*)(x + (size_t)i * 4);
    ushort4 u;
    u.x = f2bf(v.x); u.y = f2bf(v.y); u.z = f2bf(v.z); u.w = f2bf(v.w);
    *(ushort4*)(xbf + (size_t)i * 4) = u;
}

// Wt1[n][k] (512x128) = concat(Wl1,Wr1)[k][n]; Wt2[n][k] (64x256) = concat(Wl2,Wr2)[k][n]
__global__ void conv_w(const float* __restrict__ Wl1, const float* __restrict__ Wr1,
                       const float* __restrict__ Wl2, const float* __restrict__ Wr2,
                       unsigned short* __restrict__ Wt1, unsigned short* __restrict__ Wt2) {
    int idx = blockIdx.x * 256 + threadIdx.x;
    if (idx < 512 * 128) {
        int n = idx >> 7, k = idx & 127;
        float v = (n < 256) ? Wl1[(size_t)k * 256 + n] : Wr1[(size_t)k * 256 + (n - 256)];
        Wt1[idx] = f2bf(v);
    } else if (idx < 512 * 128 + 64 * 256) {
        int j = idx - 512 * 128;
        int n = j >> 8, k = j & 255;
        float v = (n < 32) ? Wl2[(size_t)k * 32 + n] : Wr2[(size_t)k * 32 + (n - 32)];
        Wt2[j] = f2bf(v);
    }
}

// ------- GEMM1 (MFMA): xbf(N,128) @ Wt1^T -> xlh (bf16, cols 0-255), xr (fp32, 256-511) ----
// Block: 32 rows x 512 cols. Wave w: cols [w*128, w*128+128) = 8 col-tiles, 2 row-tiles.
// A-frag: A[m=lane&15][k=quad*8+j]; B-frag: B[k=quad*8+j][n=lane&15]; C: row=quad*4+reg, col=lane&15.
__global__ __launch_bounds__(256) void gemm1_mfma(const unsigned short* __restrict__ xbf,
                                                  const unsigned short* __restrict__ Wt1,
                                                  unsigned short* __restrict__ xlh,
                                                  float* __restrict__ xr) {
    int wave = threadIdx.x >> 6;
    int lane = threadIdx.x & 63;
    int quad = lane >> 4, lo = lane & 15;
    int row0 = blockIdx.x * 32;
    int colw = wave * 128;
    int rA0 = min(row0 + lo, N_NODES - 1);
    int rA1 = min(row0 + 16 + lo, N_NODES - 1);
    f32x4 acc[2][8];
#pragma unroll
    for (int rt = 0; rt < 2; rt++)
#pragma unroll
        for (int ct = 0; ct < 8; ct++) acc[rt][ct] = (f32x4){0.f, 0.f, 0.f, 0.f};
#pragma unroll
    for (int ks = 0; ks < 4; ks++) {
        int koff = ks * 32 + quad * 8;
        short8 a0 = *(const short8*)(xbf + (size_t)rA0 * IN_CH + koff);
        short8 a1 = *(const short8*)(xbf + (size_t)rA1 * IN_CH + koff);
#pragma unroll
        for (int ct = 0; ct < 8; ct++) {
            short8 b = *(const short8*)(Wt1 + (size_t)(colw + ct * 16 + lo) * IN_CH + koff);
            acc[0][ct] = mfma_bf16(a0, b, acc[0][ct]);
            acc[1][ct] = mfma_bf16(a1, b, acc[1][ct]);
        }
    }
#pragma unroll
    for (int rt = 0; rt < 2; rt++) {
#pragma unroll
        for (int reg = 0; reg < 4; reg++) {
            int row = row0 + rt * 16 + quad * 4 + reg;
            if (row < N_NODES) {
#pragma unroll
                for (int ct = 0; ct < 8; ct++) {
                    int col = colw + ct * 16 + lo;
                    float v = acc[rt][ct][reg];
                    if (col < F1) xlh[(size_t)row * F1 + col] = f2bf(v);
                    else          xr[(size_t)row * F1 + (col - F1)] = v;
                }
            }
        }
    }
}

// ---------------- CSR build ----------------
__global__ void hist(const int* __restrict__ ei, int* __restrict__ deg) {
    long e = (long)blockIdx.x * 256 + threadIdx.x;
    if (e >= EP) return;
    int d = (e < N_EDGES) ? ei[N_EDGES + e] : (int)(e - N_EDGES);
    atomicAdd(&deg[d], 1);
}

__global__ void scan1(const int* __restrict__ deg, int* __restrict__ partial,
                      int* __restrict__ bsums) {
    __shared__ int tmp[256];
    int t = threadIdx.x;
    int i = blockIdx.x * 256 + t;
    tmp[t] = (i < N_NODES) ? deg[i] : 0;
    __syncthreads();
#pragma unroll
    for (int off = 1; off < 256; off <<= 1) {
        int v = (t >= off) ? tmp[t - off] : 0;
        __syncthreads();
        tmp[t] += v;
        __syncthreads();
    }
    if (i < N_NODES) partial[i] = tmp[t];
    if (t == 255) bsums[blockIdx.x] = tmp[255];
}

__global__ void scan2(int* __restrict__ bsums) {
    __shared__ int tmp[256];
    int t = threadIdx.x;
    tmp[t] = (t < NB_SCAN) ? bsums[t] : 0;
    __syncthreads();
#pragma unroll
    for (int off = 1; off < 256; off <<= 1) {
        int v = (t >= off) ? tmp[t - off] : 0;
        __syncthreads();
        tmp[t] += v;
        __syncthreads();
    }
    if (t < NB_SCAN) bsums[t] = tmp[t];
}

__global__ void scan3(const int* __restrict__ partial, const int* __restrict__ bsums,
                      const int* __restrict__ deg, int* __restrict__ row_start,
                      int* __restrict__ cur) {
    int i = blockIdx.x * 256 + threadIdx.x;
    if (i >= N_NODES) return;
    int add = (blockIdx.x > 0) ? bsums[blockIdx.x - 1] : 0;
    int excl = partial[i] + add - deg[i];
    row_start[i] = excl;
    cur[i] = excl;
}

__global__ void scatter_csr(const int* __restrict__ ei, int* __restrict__ cur,
                            int* __restrict__ srcs) {
    long e = (long)blockIdx.x * 256 + threadIdx.x;
    if (e >= EP) return;
    int s, d;
    if (e < N_EDGES) { s = ei[e]; d = ei[N_EDGES + e]; }
    else             { s = d = (int)(e - N_EDGES); }
    int pos = atomicAdd(&cur[d], 1);
    srcs[pos] = s;
}

// ------- fused L1: per-dst softmax aggregation + bias + ELU -> hbf (bf16) -------
__global__ __launch_bounds__(256) void fused_l1(const unsigned short* __restrict__ xlh,
                                                const float* __restrict__ xr1,
                                                unsigned short* __restrict__ hbf,
                                                const int* __restrict__ srcs,
                                                const int* __restrict__ row_start,
                                                const int* __restrict__ deg,
                                                const float* __restrict__ att,
                                                const float* __restrict__ bias) {
    int wave = threadIdx.x >> 6;
    int lane = threadIdx.x & 63;
    int d = blockIdx.x * 4 + wave;
    if (d >= N_NODES) return;
    int c0 = lane << 2;                 // 4 channels per lane; head = lane>>4
    float4 xr4 = *(const float4*)(xr1 + (size_t)d * F1 + c0);
    float4 at4 = *(const float4*)(att + c0);
    int start = __builtin_amdgcn_readfirstlane(row_start[d]);
    int dg    = __builtin_amdgcn_readfirstlane(deg[d]);
    int last  = dg - 1;
    float l0 = 0.f, l1 = 0.f;
    float4 acc0 = make_float4(0.f, 0.f, 0.f, 0.f);
    float4 acc1 = make_float4(0.f, 0.f, 0.f, 0.f);
    int sA = srcs[start];
    int sB = srcs[start + min(1, last)];
    ushort4 rawA = *(const ushort4*)(xlh + (size_t)sA * F1 + c0);
    ushort4 rawB = *(const ushort4*)(xlh + (size_t)sB * F1 + c0);
    int npairs = dg >> 1;
    for (int k = 0; k < npairs; k++) {
        int j = 2 * k;
        ushort4 cA = rawA, cB = rawB;
        int nA = srcs[start + min(j + 2, last)];
        int nB = srcs[start + min(j + 3, last)];
        rawA = *(const ushort4*)(xlh + (size_t)nA * F1 + c0);
        rawB = *(const ushort4*)(xlh + (size_t)nB * F1 + c0);
        {
            float ax = bf2f(cA.x), ay = bf2f(cA.y), az = bf2f(cA.z), aw = bf2f(cA.w);
            float v0 = ax + xr4.x; v0 = fmaxf(v0, NEG * v0);
            float v1 = ay + xr4.y; v1 = fmaxf(v1, NEG * v1);
            float v2 = az + xr4.z; v2 = fmaxf(v2, NEG * v2);
            float v3 = aw + xr4.w; v3 = fmaxf(v3, NEG * v3);
            float sc = v0 * at4.x + v1 * at4.y + v2 * at4.z + v3 * at4.w;
            sc += __shfl_xor(sc, 1);
            sc += __shfl_xor(sc, 2);
            sc += __shfl_xor(sc, 4);
            sc += __shfl_xor(sc, 8);
            float ex = __expf(sc);
            l0 += ex;
            acc0.x += ex * ax; acc0.y += ex * ay;
            acc0.z += ex * az; acc0.w += ex * aw;
        }
        {
            float ax = bf2f(cB.x), ay = bf2f(cB.y), az = bf2f(cB.z), aw = bf2f(cB.w);
            float v0 = ax + xr4.x; v0 = fmaxf(v0, NEG * v0);
            float v1 = ay + xr4.y; v1 = fmaxf(v1, NEG * v1);
            float v2 = az + xr4.z; v2 = fmaxf(v2, NEG * v2);
            float v3 = aw + xr4.w; v3 = fmaxf(v3, NEG * v3);
            float sc = v0 * at4.x + v1 * at4.y + v2 * at4.z + v3 * at4.w;
            sc += __shfl_xor(sc, 1);
            sc += __shfl_xor(sc, 2);
            sc += __shfl_xor(sc, 4);
            sc += __shfl_xor(sc, 8);
            float ex = __expf(sc);
            l1 += ex;
            acc1.x += ex * ax; acc1.y += ex * ay;
            acc1.z += ex * az; acc1.w += ex * aw;
        }
    }
    if (dg & 1) {
        float ax = bf2f(rawA.x), ay = bf2f(rawA.y), az = bf2f(rawA.z), aw = bf2f(rawA.w);
        float v0 = ax + xr4.x; v0 = fmaxf(v0, NEG * v0);
        float v1 = ay + xr4.y; v1 = fmaxf(v1, NEG * v1);
        float v2 = az + xr4.z; v2 = fmaxf(v2, NEG * v2);
        float v3 = aw + xr4.w; v3 = fmaxf(v3, NEG * v3);
        float sc = v0 * at4.x + v1 * at4.y + v2 * at4.z + v3 * at4.w;
        sc += __shfl_xor(sc, 1);
        sc += __shfl_xor(sc, 2);
        sc += __shfl_xor(sc, 4);
        sc += __shfl_xor(sc, 8);
        float ex = __expf(sc);
        l0 += ex;
        acc0.x += ex * ax; acc0.y += ex * ay;
        acc0.z += ex * az; acc0.w += ex * aw;
    }
    float inv = 1.0f / (l0 + l1);
    float4 b4 = *(const float4*)(bias + c0);
    float o0 = (acc0.x + acc1.x) * inv + b4.x; o0 = o0 > 0.f ? o0 : __expf(o0) - 1.0f;
    float o1 = (acc0.y + acc1.y) * inv + b4.y; o1 = o1 > 0.f ? o1 : __expf(o1) - 1.0f;
    float o2 = (acc0.z + acc1.z) * inv + b4.z; o2 = o2 > 0.f ? o2 : __expf(o2) - 1.0f;
    float o3 = (acc0.w + acc1.w) * inv + b4.w; o3 = o3 > 0.f ? o3 : __expf(o3) - 1.0f;
    ushort4 ho;
    ho.x = f2bf(o0); ho.y = f2bf(o1); ho.z = f2bf(o2); ho.w = f2bf(o3);
    *(ushort4*)(hbf + (size_t)d * F1 + c0) = ho;
}

// ---- GEMM2 (MFMA): hbf(N,256) @ Wt2^T -> xl2h (fp16, cols 0-31), xr2 (fp32, 32-63) ----
__global__ __launch_bounds__(256) void gemm2_mfma(const unsigned short* __restrict__ hbf,
                                                  const unsigned short* __restrict__ Wt2,
                                                  __half* __restrict__ xl2h,
                                                  float* __restrict__ xr2) {
    int wave = threadIdx.x >> 6;
    int lane = threadIdx.x & 63;
    int quad = lane >> 4, lo = lane & 15;
    int row0 = blockIdx.x * 64 + wave * 16;
    int rA = min(row0 + lo, N_NODES - 1);
    f32x4 acc[4];
#pragma unroll
    for (int ct = 0; ct < 4; ct++) acc[ct] = (f32x4){0.f, 0.f, 0.f, 0.f};
#pragma unroll
    for (int ks = 0; ks < 8; ks++) {
        int koff = ks * 32 + quad * 8;
        short8 a = *(const short8*)(hbf + (size_t)rA * F1 + koff);
#pragma unroll
        for (int ct = 0; ct < 4; ct++) {
            short8 b = *(const short8*)(Wt2 + (size_t)(ct * 16 + lo) * F1 + koff);
            acc[ct] = mfma_bf16(a, b, acc[ct]);
        }
    }
#pragma unroll
    for (int reg = 0; reg < 4; reg++) {
        int row = row0 + quad * 4 + reg;
        if (row < N_NODES) {
#pragma unroll
            for (int ct = 0; ct < 4; ct++) {
                int col = ct * 16 + lo;
                float v = acc[ct][reg];
                if (col < LAT) xl2h[(size_t)row * LAT + col] = __float2half_rn(v);
                else           xr2[(size_t)row * LAT + (col - LAT)] = v;
            }
        }
    }
}

// ------- fused L2: one dst per wave; lanes 0-31 = even edges, 32-63 = odd edges -------
__global__ __launch_bounds__(256) void fused_l2(const __half* __restrict__ xl2h,
                                                const float* __restrict__ xr2,
                                                const int* __restrict__ srcs,
                                                const int* __restrict__ row_start,
                                                const int* __restrict__ deg,
                                                const float* __restrict__ att,
                                                const float* __restrict__ bias,
                                                __half* __restrict__ zh) {
    int wave = threadIdx.x >> 6;
    int lane = threadIdx.x & 63;
    int hw = lane >> 5;
    int c = lane & 31;
    int d = blockIdx.x * 4 + wave;
    if (d >= N_NODES) return;
    float xr = xr2[(size_t)d * LAT + c];
    float av = att[c];
    int start = __builtin_amdgcn_readfirstlane(row_start[d]);
    int dg    = __builtin_amdgcn_readfirstlane(deg[d]);
    int last  = dg - 1;
    float l = 0.f, acc = 0.f;
    int jj = hw;
    int sA = srcs[start + min(jj, last)];
    float aA = __half2float(xl2h[(size_t)sA * LAT + c]);
    int sN = srcs[start + min(jj + 2, last)];
    int iters = (dg + 1) >> 1;
    for (int k = 0; k < iters; k++) {
        float a = aA;
        aA = __half2float(xl2h[(size_t)sN * LAT + c]);
        sN = srcs[start + min(jj + 4, last)];
        float v = a + xr; v = fmaxf(v, NEG * v);
        float sc = v * av;
        sc += __shfl_xor(sc, 1);
        sc += __shfl_xor(sc, 2);
        sc += __shfl_xor(sc, 4);
        sc += __shfl_xor(sc, 8);
        sc += __shfl_xor(sc, 16);
        float ex = (jj < dg) ? __expf(sc) : 0.f;
        l += ex;
        acc += ex * a;
        jj += 2;
    }
    l += __shfl_xor(l, 32);
    acc += __shfl_xor(acc, 32);
    if (hw == 0)
        zh[(size_t)d * LAT + c] = __float2half_rn(acc / l + bias[c]);
}

// ------- decode: sigmoid(<z[row], z[col]>), z fp16, 16 lanes / edge, half2 loads -------
__global__ __launch_bounds__(256) void decode(const __half* __restrict__ zh,
                                              const int* __restrict__ ei,
                                              float* __restrict__ out) {
    int g = threadIdx.x >> 4;
    int lane = threadIdx.x & 15;
    long e = (long)blockIdx.x * 16 + g;
    if (e >= N_EDGES) return;
    int r = ei[e], c = ei[N_EDGES + e];
    int cc = lane << 1;
    __half2 zr = *(const __half2*)(zh + (size_t)r * LAT + cc);
    __half2 zc = *(const __half2*)(zh + (size_t)c * LAT + cc);
    float v = __half2float(zr.x) * __half2float(zc.x)
            + __half2float(zr.y) * __half2float(zc.y);
    v += __shfl_xor(v, 1);
    v += __shfl_xor(v, 2);
    v += __shfl_xor(v, 4);
    v += __shfl_xor(v, 8);
    if (lane == 0) out[e] = 1.0f / (1.0f + __expf(-v));
}

extern "C" void kernel_launch(void* const* d_in, const int* in_sizes, int n_in,
                              void* d_out, int out_size, void* d_ws, size_t ws_size,
                              hipStream_t stream) {
    const float* x    = (const float*)d_in[0];
    const int*   ei   = (const int*)d_in[1];
    const float* Wl1  = (const float*)d_in[2];
    const float* Wr1  = (const float*)d_in[3];
    const float* att1 = (const float*)d_in[4];
    const float* b1   = (const float*)d_in[5];
    const float* Wl2  = (const float*)d_in[6];
    const float* Wr2  = (const float*)d_in[7];
    const float* att2 = (const float*)d_in[8];
    const float* b2   = (const float*)d_in[9];
    float* out = (float*)d_out;

    float* ws   = (float*)d_ws;
    float* xr1  = ws;                                            // N*256 fp32 (51.2 MB)
    unsigned short* hbf = (unsigned short*)(xr1 + (size_t)N_NODES * F1);  // N*256 bf16 (25.6 MB)
    unsigned short* xbf = hbf;                                   // N*128 bf16 — dead before hbf written
    unsigned short* xlh = hbf + (size_t)N_NODES * F1;            // N*256 bf16 (25.6 MB)
    int* deg       = (int*)(xlh + (size_t)N_NODES * F1);
    int* row_start = deg + N_NODES;
    int* cur       = row_start + N_NODES;
    int* partial   = cur + N_NODES;
    int* bsums     = partial + N_NODES;
    int* srcs      = bsums + 256;                                // EP ints (3.4 MB)
    unsigned short* Wt1 = (unsigned short*)(srcs + EP);          // 512*128 bf16
    unsigned short* Wt2 = Wt1 + 512 * 128;                       // 64*256 bf16
    // layer-2 buffers reuse the xlh region (dead after fused_l1): 12.8 MB
    __half* xl2h = (__half*)xlh;                                 // N*32 fp16
    float*  xr2  = (float*)(xl2h + (size_t)N_NODES * LAT);
    __half* zh   = (__half*)(xr2 + (size_t)N_NODES * LAT);

    // ---- prep: bf16 conversions ----
    conv_x<<<(N_NODES * IN_CH / 4 + 255) / 256, 256, 0, stream>>>(x, xbf);
    conv_w<<<(512 * 128 + 64 * 256 + 255) / 256, 256, 0, stream>>>(Wl1, Wr1, Wl2, Wr2, Wt1, Wt2);
    hipMemsetAsync(deg, 0, N_NODES * sizeof(int), stream);

    // ---- layer-1 GEMM (MFMA) ----
    gemm1_mfma<<<(N_NODES + 31) / 32, 256, 0, stream>>>(xbf, Wt1, xlh, xr1);

    // ---- CSR build (graph is identical for both layers) ----
    hist<<<(EP + 255) / 256, 256, 0, stream>>>(ei, deg);
    scan1<<<NB_SCAN, 256, 0, stream>>>(deg, partial, bsums);
    scan2<<<1, 256, 0, stream>>>(bsums);
    scan3<<<NB_SCAN, 256, 0, stream>>>(partial, bsums, deg, row_start, cur);
    scatter_csr<<<(EP + 255) / 256, 256, 0, stream>>>(ei, cur, srcs);

    // ---- layer 1 aggregate (writes hbf) ----
    fused_l1<<<(N_NODES + 3) / 4, 256, 0, stream>>>(xlh, xr1, hbf, srcs, row_start, deg, att1, b1);

    // ---- layer 2 ----
    gemm2_mfma<<<(N_NODES + 63) / 64, 256, 0, stream>>>(hbf, Wt2, xl2h, xr2);
    fused_l2<<<(N_NODES + 3) / 4, 256, 0, stream>>>(xl2h, xr2, srcs, row_start, deg, att2, b2, zh);

    // ---- decode ----
    decode<<<(N_EDGES + 15) / 16, 256, 0, stream>>>(zh, ei, out);
}

// Round 8
// 374.774 us; speedup vs baseline: 1.4427x; 1.0617x over previous
//
#include <hip/hip_runtime.h>
#include <hip/hip_fp16.h>
#include <math.h>

#define N_NODES 50000
#define N_EDGES 800000
#define EP (N_EDGES + N_NODES)   /* 850000 with self loops */
#define IN_CH 128
#define HID 64
#define HEADS 4
#define F1 (HEADS * HID)         /* 256 */
#define LAT 32
#define NEG 0.2f
#define NB_SCAN ((N_NODES + 255) / 256)   /* 196 blocks */

typedef __attribute__((ext_vector_type(8))) short short8;
typedef __attribute__((ext_vector_type(8))) unsigned short ushort8v;
typedef __attribute__((ext_vector_type(4))) float f32x4;

__device__ __forceinline__ unsigned short f2bf(float f) {
    unsigned int x = __float_as_uint(f);
    x += 0x7fffu + ((x >> 16) & 1u);       // round-to-nearest-even
    return (unsigned short)(x >> 16);
}
__device__ __forceinline__ float bf2f(unsigned short u) {
    return __uint_as_float(((unsigned int)u) << 16);
}
__device__ __forceinline__ f32x4 mfma_bf16(short8 a, short8 b, f32x4 c) {
    return __builtin_amdgcn_mfma_f32_16x16x32_bf16(a, b, c, 0, 0, 0);
}

// ---------------- prep: fp32 -> bf16 conversions ----------------
__global__ void conv_x(const float* __restrict__ x, unsigned short* __restrict__ xbf) {
    int i = blockIdx.x * 256 + threadIdx.x;          // one float4 per thread
    if (i >= N_NODES * IN_CH / 4) return;
    float4 v = *(const float4*)(x + (size_t)i * 4);
    ushort4 u;
    u.x = f2bf(v.x); u.y = f2bf(v.y); u.z = f2bf(v.z); u.w = f2bf(v.w);
    *(ushort4*)(xbf + (size_t)i * 4) = u;
}

// Wt1[n][k] (512x128) = concat(Wl1,Wr1)[k][n]; Wt2[n][k] (64x256) = concat(Wl2,Wr2)[k][n]
__global__ void conv_w(const float* __restrict__ Wl1, const float* __restrict__ Wr1,
                       const float* __restrict__ Wl2, const float* __restrict__ Wr2,
                       unsigned short* __restrict__ Wt1, unsigned short* __restrict__ Wt2) {
    int idx = blockIdx.x * 256 + threadIdx.x;
    if (idx < 512 * 128) {
        int n = idx >> 7, k = idx & 127;
        float v = (n < 256) ? Wl1[(size_t)k * 256 + n] : Wr1[(size_t)k * 256 + (n - 256)];
        Wt1[idx] = f2bf(v);
    } else if (idx < 512 * 128 + 64 * 256) {
        int j = idx - 512 * 128;
        int n = j >> 8, k = j & 255;
        float v = (n < 32) ? Wl2[(size_t)k * 32 + n] : Wr2[(size_t)k * 32 + (n - 32)];
        Wt2[j] = f2bf(v);
    }
}

// ------- GEMM1 (MFMA): xbf(N,128) @ Wt1^T -> xlh (bf16, cols 0-255), xr (fp32, 256-511) ----
__global__ __launch_bounds__(256) void gemm1_mfma(const unsigned short* __restrict__ xbf,
                                                  const unsigned short* __restrict__ Wt1,
                                                  unsigned short* __restrict__ xlh,
                                                  float* __restrict__ xr) {
    int wave = threadIdx.x >> 6;
    int lane = threadIdx.x & 63;
    int quad = lane >> 4, lo = lane & 15;
    int row0 = blockIdx.x * 32;
    int colw = wave * 128;
    int rA0 = min(row0 + lo, N_NODES - 1);
    int rA1 = min(row0 + 16 + lo, N_NODES - 1);
    f32x4 acc[2][8];
#pragma unroll
    for (int rt = 0; rt < 2; rt++)
#pragma unroll
        for (int ct = 0; ct < 8; ct++) acc[rt][ct] = (f32x4){0.f, 0.f, 0.f, 0.f};
#pragma unroll
    for (int ks = 0; ks < 4; ks++) {
        int koff = ks * 32 + quad * 8;
        short8 a0 = *(const short8*)(xbf + (size_t)rA0 * IN_CH + koff);
        short8 a1 = *(const short8*)(xbf + (size_t)rA1 * IN_CH + koff);
#pragma unroll
        for (int ct = 0; ct < 8; ct++) {
            short8 b = *(const short8*)(Wt1 + (size_t)(colw + ct * 16 + lo) * IN_CH + koff);
            acc[0][ct] = mfma_bf16(a0, b, acc[0][ct]);
            acc[1][ct] = mfma_bf16(a1, b, acc[1][ct]);
        }
    }
#pragma unroll
    for (int rt = 0; rt < 2; rt++) {
#pragma unroll
        for (int reg = 0; reg < 4; reg++) {
            int row = row0 + rt * 16 + quad * 4 + reg;
            if (row < N_NODES) {
#pragma unroll
                for (int ct = 0; ct < 8; ct++) {
                    int col = colw + ct * 16 + lo;
                    float v = acc[rt][ct][reg];
                    if (col < F1) xlh[(size_t)row * F1 + col] = f2bf(v);
                    else          xr[(size_t)row * F1 + (col - F1)] = v;
                }
            }
        }
    }
}

// ---------------- CSR build ----------------
__global__ void hist(const int* __restrict__ ei, int* __restrict__ deg) {
    long e = (long)blockIdx.x * 256 + threadIdx.x;
    if (e >= EP) return;
    int d = (e < N_EDGES) ? ei[N_EDGES + e] : (int)(e - N_EDGES);
    atomicAdd(&deg[d], 1);
}

__global__ void scan1(const int* __restrict__ deg, int* __restrict__ partial,
                      int* __restrict__ bsums) {
    __shared__ int tmp[256];
    int t = threadIdx.x;
    int i = blockIdx.x * 256 + t;
    tmp[t] = (i < N_NODES) ? deg[i] : 0;
    __syncthreads();
#pragma unroll
    for (int off = 1; off < 256; off <<= 1) {
        int v = (t >= off) ? tmp[t - off] : 0;
        __syncthreads();
        tmp[t] += v;
        __syncthreads();
    }
    if (i < N_NODES) partial[i] = tmp[t];
    if (t == 255) bsums[blockIdx.x] = tmp[255];
}

__global__ void scan2(int* __restrict__ bsums) {
    __shared__ int tmp[256];
    int t = threadIdx.x;
    tmp[t] = (t < NB_SCAN) ? bsums[t] : 0;
    __syncthreads();
#pragma unroll
    for (int off = 1; off < 256; off <<= 1) {
        int v = (t >= off) ? tmp[t - off] : 0;
        __syncthreads();
        tmp[t] += v;
        __syncthreads();
    }
    if (t < NB_SCAN) bsums[t] = tmp[t];
}

__global__ void scan3(const int* __restrict__ partial, const int* __restrict__ bsums,
                      const int* __restrict__ deg, int* __restrict__ row_start,
                      int* __restrict__ cur) {
    int i = blockIdx.x * 256 + threadIdx.x;
    if (i >= N_NODES) return;
    int add = (blockIdx.x > 0) ? bsums[blockIdx.x - 1] : 0;
    int excl = partial[i] + add - deg[i];
    row_start[i] = excl;
    cur[i] = excl;
}

__global__ void scatter_csr(const int* __restrict__ ei, int* __restrict__ cur,
                            int* __restrict__ srcs) {
    long e = (long)blockIdx.x * 256 + threadIdx.x;
    if (e >= EP) return;
    int s, d;
    if (e < N_EDGES) { s = ei[e]; d = ei[N_EDGES + e]; }
    else             { s = d = (int)(e - N_EDGES); }
    int pos = atomicAdd(&cur[d], 1);
    srcs[pos] = s;
}

// ------- fused L1: per-dst softmax aggregation + bias + ELU -> hbf (bf16) -------
// One dst per wave. 8 ch/lane (16B gather loads); half-wave = edge parity -> 2 edges
// per iter, 4 gather rows in flight. Head = 8 lanes -> 3-round shfl reduce; per-head
// softmax state lives per-lane (lane group == head).
__global__ __launch_bounds__(256) void fused_l1(const unsigned short* __restrict__ xlh,
                                                const float* __restrict__ xr1,
                                                unsigned short* __restrict__ hbf,
                                                const int* __restrict__ srcs,
                                                const int* __restrict__ row_start,
                                                const int* __restrict__ deg,
                                                const float* __restrict__ att,
                                                const float* __restrict__ bias) {
    int wave = threadIdx.x >> 6;
    int lane = threadIdx.x & 63;
    int h = lane >> 5;                  // edge parity
    int c = lane & 31;                  // channel-lane: ch c*8 .. c*8+7 (head = c>>3)
    int c0 = c << 3;
    int d = blockIdx.x * 4 + wave;
    if (d >= N_NODES) return;
    float4 xrA = *(const float4*)(xr1 + (size_t)d * F1 + c0);
    float4 xrB = *(const float4*)(xr1 + (size_t)d * F1 + c0 + 4);
    float4 atA = *(const float4*)(att + c0);
    float4 atB = *(const float4*)(att + c0 + 4);
    float xr8[8] = {xrA.x, xrA.y, xrA.z, xrA.w, xrB.x, xrB.y, xrB.z, xrB.w};
    float at8[8] = {atA.x, atA.y, atA.z, atA.w, atB.x, atB.y, atB.z, atB.w};
    int start = __builtin_amdgcn_readfirstlane(row_start[d]);
    int dg    = __builtin_amdgcn_readfirstlane(deg[d]);
    int last  = dg - 1;
    float l = 0.f;
    float acc[8] = {};
    int jj = h;                          // this half's edges: h, h+2, h+4, ...
    int s = srcs[start + min(jj, last)];
    ushort8v raw = *(const ushort8v*)(xlh + (size_t)s * F1 + c0);
    int sN = srcs[start + min(jj + 2, last)];
    int iters = (dg + 1) >> 1;
    for (int k = 0; k < iters; k++) {
        ushort8v cr = raw;
        raw = *(const ushort8v*)(xlh + (size_t)sN * F1 + c0);
        sN = srcs[start + min(jj + 4, last)];
        float a[8];
#pragma unroll
        for (int i = 0; i < 8; i++) a[i] = bf2f(cr[i]);
        float sc = 0.f;
#pragma unroll
        for (int i = 0; i < 8; i++) {
            float v = a[i] + xr8[i];
            v = fmaxf(v, NEG * v);
            sc += v * at8[i];
        }
        // reduce over the 8 lanes of this head (xor <= 7 stays in head & half)
        sc += __shfl_xor(sc, 1);
        sc += __shfl_xor(sc, 2);
        sc += __shfl_xor(sc, 4);
        float ex = (jj < dg) ? __expf(sc) : 0.f;
        l += ex;
#pragma unroll
        for (int i = 0; i < 8; i++) acc[i] += ex * a[i];
        jj += 2;
    }
    // combine the two halves (channel mapping identical across halves)
    l += __shfl_xor(l, 32);
#pragma unroll
    for (int i = 0; i < 8; i++) acc[i] += __shfl_xor(acc[i], 32);
    if (h == 0) {
        float inv = 1.0f / l;
        float4 bA = *(const float4*)(bias + c0);
        float4 bB = *(const float4*)(bias + c0 + 4);
        float b8[8] = {bA.x, bA.y, bA.z, bA.w, bB.x, bB.y, bB.z, bB.w};
        ushort8v ho;
#pragma unroll
        for (int i = 0; i < 8; i++) {
            float o = acc[i] * inv + b8[i];
            o = o > 0.f ? o : __expf(o) - 1.0f;
            ho[i] = (unsigned short)f2bf(o);
        }
        *(ushort8v*)(hbf + (size_t)d * F1 + c0) = ho;
    }
}

// ---- GEMM2 (MFMA): hbf(N,256) @ Wt2^T -> xl2h (fp16, cols 0-31), xr2 (fp32, 32-63) ----
__global__ __launch_bounds__(256) void gemm2_mfma(const unsigned short* __restrict__ hbf,
                                                  const unsigned short* __restrict__ Wt2,
                                                  __half* __restrict__ xl2h,
                                                  float* __restrict__ xr2) {
    int wave = threadIdx.x >> 6;
    int lane = threadIdx.x & 63;
    int quad = lane >> 4, lo = lane & 15;
    int row0 = blockIdx.x * 64 + wave * 16;
    int rA = min(row0 + lo, N_NODES - 1);
    f32x4 acc[4];
#pragma unroll
    for (int ct = 0; ct < 4; ct++) acc[ct] = (f32x4){0.f, 0.f, 0.f, 0.f};
#pragma unroll
    for (int ks = 0; ks < 8; ks++) {
        int koff = ks * 32 + quad * 8;
        short8 a = *(const short8*)(hbf + (size_t)rA * F1 + koff);
#pragma unroll
        for (int ct = 0; ct < 4; ct++) {
            short8 b = *(const short8*)(Wt2 + (size_t)(ct * 16 + lo) * F1 + koff);
            acc[ct] = mfma_bf16(a, b, acc[ct]);
        }
    }
#pragma unroll
    for (int reg = 0; reg < 4; reg++) {
        int row = row0 + quad * 4 + reg;
        if (row < N_NODES) {
#pragma unroll
            for (int ct = 0; ct < 4; ct++) {
                int col = ct * 16 + lo;
                float v = acc[ct][reg];
                if (col < LAT) xl2h[(size_t)row * LAT + col] = __float2half_rn(v);
                else           xr2[(size_t)row * LAT + (col - LAT)] = v;
            }
        }
    }
}

// ------- fused L2: one dst per wave; quarter-wave per edge -> 4 edges/iter, 2 ch/lane ----
__global__ __launch_bounds__(256) void fused_l2(const __half* __restrict__ xl2h,
                                                const float* __restrict__ xr2,
                                                const int* __restrict__ srcs,
                                                const int* __restrict__ row_start,
                                                const int* __restrict__ deg,
                                                const float* __restrict__ att,
                                                const float* __restrict__ bias,
                                                __half* __restrict__ zh) {
    int wave = threadIdx.x >> 6;
    int lane = threadIdx.x & 63;
    int q = lane >> 4;                  // edge parity class 0..3
    int c = lane & 15;                  // channel-lane: ch 2c, 2c+1
    int c2 = c << 1;
    int d = blockIdx.x * 4 + wave;
    if (d >= N_NODES) return;
    float xr0 = xr2[(size_t)d * LAT + c2];
    float xr1v = xr2[(size_t)d * LAT + c2 + 1];
    float av0 = att[c2], av1 = att[c2 + 1];
    int start = __builtin_amdgcn_readfirstlane(row_start[d]);
    int dg    = __builtin_amdgcn_readfirstlane(deg[d]);
    int last  = dg - 1;
    float l = 0.f, acc0 = 0.f, acc1 = 0.f;
    int jj = q;                         // this quarter's edges: q, q+4, q+8, ...
    int s = srcs[start + min(jj, last)];
    __half2 raw = *(const __half2*)(xl2h + (size_t)s * LAT + c2);
    int sN = srcs[start + min(jj + 4, last)];
    int iters = (dg + 3) >> 2;
    for (int k = 0; k < iters; k++) {
        __half2 cr = raw;
        raw = *(const __half2*)(xl2h + (size_t)sN * LAT + c2);
        sN = srcs[start + min(jj + 8, last)];
        float a0 = __half2float(cr.x), a1 = __half2float(cr.y);
        float v0 = a0 + xr0;  v0 = fmaxf(v0, NEG * v0);
        float v1 = a1 + xr1v; v1 = fmaxf(v1, NEG * v1);
        float sc = v0 * av0 + v1 * av1;
        sc += __shfl_xor(sc, 1);
        sc += __shfl_xor(sc, 2);
        sc += __shfl_xor(sc, 4);
        sc += __shfl_xor(sc, 8);
        float ex = (jj < dg) ? __expf(sc) : 0.f;
        l += ex;
        acc0 += ex * a0;
        acc1 += ex * a1;
        jj += 4;
    }
    // combine the 4 quarters
    l += __shfl_xor(l, 16); acc0 += __shfl_xor(acc0, 16); acc1 += __shfl_xor(acc1, 16);
    l += __shfl_xor(l, 32); acc0 += __shfl_xor(acc0, 32); acc1 += __shfl_xor(acc1, 32);
    if (q == 0) {
        __half2 o;
        o.x = __float2half_rn(acc0 / l + bias[c2]);
        o.y = __float2half_rn(acc1 / l + bias[c2 + 1]);
        *(__half2*)(zh + (size_t)d * LAT + c2) = o;
    }
}

// ------- decode: sigmoid(<z[row], z[col]>), z fp16, 8 lanes/edge, 8B loads ----
__global__ __launch_bounds__(256) void decode(const __half* __restrict__ zh,
                                              const int* __restrict__ ei,
                                              float* __restrict__ out) {
    int g = threadIdx.x >> 3;             // 32 edge-groups per block
    int lane = threadIdx.x & 7;
    long e = (long)blockIdx.x * 32 + g;
    if (e >= N_EDGES) return;
    int r = ei[e], c = ei[N_EDGES + e];
    int cc = lane << 2;                   // 4 channels
    ushort4 ur = *(const ushort4*)(zh + (size_t)r * LAT + cc);
    ushort4 uc = *(const ushort4*)(zh + (size_t)c * LAT + cc);
    __half2 r01 = *(__half2*)&ur.x, r23 = *(__half2*)&ur.z;
    __half2 c01 = *(__half2*)&uc.x, c23 = *(__half2*)&uc.z;
    float v = __half2float(r01.x) * __half2float(c01.x)
            + __half2float(r01.y) * __half2float(c01.y)
            + __half2float(r23.x) * __half2float(c23.x)
            + __half2float(r23.y) * __half2float(c23.y);
    v += __shfl_xor(v, 1);
    v += __shfl_xor(v, 2);
    v += __shfl_xor(v, 4);
    if (lane == 0) out[e] = 1.0f / (1.0f + __expf(-v));
}

extern "C" void kernel_launch(void* const* d_in, const int* in_sizes, int n_in,
                              void* d_out, int out_size, void* d_ws, size_t ws_size,
                              hipStream_t stream) {
    const float* x    = (const float*)d_in[0];
    const int*   ei   = (const int*)d_in[1];
    const float* Wl1  = (const float*)d_in[2];
    const float* Wr1  = (const float*)d_in[3];
    const float* att1 = (const float*)d_in[4];
    const float* b1   = (const float*)d_in[5];
    const float* Wl2  = (const float*)d_in[6];
    const float* Wr2  = (const float*)d_in[7];
    const float* att2 = (const float*)d_in[8];
    const float* b2   = (const float*)d_in[9];
    float* out = (float*)d_out;

    float* ws   = (float*)d_ws;
    float* xr1  = ws;                                            // N*256 fp32 (51.2 MB)
    unsigned short* hbf = (unsigned short*)(xr1 + (size_t)N_NODES * F1);  // N*256 bf16 (25.6 MB)
    unsigned short* xbf = hbf;                                   // N*128 bf16 — dead before hbf written
    unsigned short* xlh = hbf + (size_t)N_NODES * F1;            // N*256 bf16 (25.6 MB)
    int* deg       = (int*)(xlh + (size_t)N_NODES * F1);
    int* row_start = deg + N_NODES;
    int* cur       = row_start + N_NODES;
    int* partial   = cur + N_NODES;
    int* bsums     = partial + N_NODES;
    int* srcs      = bsums + 256;                                // EP ints (3.4 MB)
    unsigned short* Wt1 = (unsigned short*)(srcs + EP);          // 512*128 bf16
    unsigned short* Wt2 = Wt1 + 512 * 128;                       // 64*256 bf16
    // layer-2 buffers reuse the xlh region (dead after fused_l1): 12.8 MB
    __half* xl2h = (__half*)xlh;                                 // N*32 fp16
    float*  xr2  = (float*)(xl2h + (size_t)N_NODES * LAT);
    __half* zh   = (__half*)(xr2 + (size_t)N_NODES * LAT);

    // ---- prep: bf16 conversions ----
    conv_x<<<(N_NODES * IN_CH / 4 + 255) / 256, 256, 0, stream>>>(x, xbf);
    conv_w<<<(512 * 128 + 64 * 256 + 255) / 256, 256, 0, stream>>>(Wl1, Wr1, Wl2, Wr2, Wt1, Wt2);
    hipMemsetAsync(deg, 0, N_NODES * sizeof(int), stream);

    // ---- layer-1 GEMM (MFMA) ----
    gemm1_mfma<<<(N_NODES + 31) / 32, 256, 0, stream>>>(xbf, Wt1, xlh, xr1);

    // ---- CSR build (graph is identical for both layers) ----
    hist<<<(EP + 255) / 256, 256, 0, stream>>>(ei, deg);
    scan1<<<NB_SCAN, 256, 0, stream>>>(deg, partial, bsums);
    scan2<<<1, 256, 0, stream>>>(bsums);
    scan3<<<NB_SCAN, 256, 0, stream>>>(partial, bsums, deg, row_start, cur);
    scatter_csr<<<(EP + 255) / 256, 256, 0, stream>>>(ei, cur, srcs);

    // ---- layer 1 aggregate (writes hbf) ----
    fused_l1<<<(N_NODES + 3) / 4, 256, 0, stream>>>(xlh, xr1, hbf, srcs, row_start, deg, att1, b1);

    // ---- layer 2 ----
    gemm2_mfma<<<(N_NODES + 63) / 64, 256, 0, stream>>>(hbf, Wt2, xl2h, xr2);
    fused_l2<<<(N_NODES + 3) / 4, 256, 0, stream>>>(xl2h, xr2, srcs, row_start, deg, att2, b2, zh);

    // ---- decode ----
    decode<<<(N_EDGES + 31) / 32, 256, 0, stream>>>(zh, ei, out);
}